// Round 4
// baseline (1070.334 us; speedup 1.0000x reference)
//
#include <hip/hip_runtime.h>
#include <hip/hip_bf16.h>

#define TT 4
#define BB 16
#define VV 128
#define EE 512
#define HIDC 2048
#define BN_EPS 1e-5f

typedef unsigned int u32;
typedef unsigned long long u64;
typedef unsigned char u8;
typedef unsigned short u16;

// ---------------- per-layer weight transpose: WT[c][o] ----------------
__global__ __launch_bounds__(256) void trans6(const float* __restrict__ qw,
    const float* __restrict__ f1w, const float* __restrict__ f2w,
    float* __restrict__ wq, float* __restrict__ w1, float* __restrict__ w2)
{
  const int zz = blockIdx.y;
  const float* src; float* dst; int O, C;
  if (zz < 4)      { src = qw + (size_t)zz * EE * EE; dst = wq + (size_t)zz * EE * EE; O = EE;   C = EE; }
  else if (zz == 4){ src = f1w; dst = w1; O = HIDC; C = EE; }
  else             { src = f2w; dst = w2; O = EE;   C = HIDC; }
  const int tc_n = C >> 5, to_n = O >> 5;
  const int bx = blockIdx.x;
  if (bx >= tc_n * to_n) return;
  const int tc = bx % tc_n, to = bx / tc_n;
  __shared__ float t[32][33];
  const int tx = threadIdx.x & 31, ty = threadIdx.x >> 5;   // 32x8
#pragma unroll
  for (int k = 0; k < 4; ++k) {
    int o = to * 32 + ty + k * 8, c = tc * 32 + tx;
    t[ty + k * 8][tx] = src[(size_t)o * C + c];
  }
  __syncthreads();
#pragma unroll
  for (int k = 0; k < 4; ++k) {
    int c = tc * 32 + ty + k * 8, o = to * 32 + tx;
    dst[(size_t)c * O + o] = t[tx][ty + k * 8];
  }
}

// ---------------- patch embed + BN + LIF + flags (wave = one (b,e) channel) ----------------
__global__ __launch_bounds__(256) void pe_lif(const float* __restrict__ x,
    const float* __restrict__ w, const float* __restrict__ bnp,
    float* __restrict__ h, float* __restrict__ spk, u8* __restrict__ flags)
{
  const int g = blockIdx.x * 4 + (threadIdx.x >> 6);
  const int lane = threadIdx.x & 63;
  const int b = g >> 9, e = g & 511;
  const float w0 = w[e * 2], w1 = w[e * 2 + 1];
  const float gg = bnp[e], be = bnp[EE + e], mm = bnp[2 * EE + e], vr = bnp[3 * EE + e];
  const float sc = gg / sqrtf(vr + BN_EPS);
  float v0 = 0.f, v1 = 0.f;
#pragma unroll
  for (int t = 0; t < TT; ++t) {
    const int tb = t * BB + b;
    const float* xb = x + (size_t)tb * 2 * VV;
    float x00 = xb[lane], x01 = xb[lane + 64];
    float x10 = xb[VV + lane], x11 = xb[VV + lane + 64];
    float a0 = (w0 * x00 + w1 * x10 - mm) * sc + be;
    float a1 = (w0 * x01 + w1 * x11 - mm) * sc + be;
    size_t o = ((size_t)tb * EE + e) * VV + lane;
    h[o] = a0; h[o + 64] = a1;
    v0 += (a0 - v0) * 0.5f; v1 += (a1 - v1) * 0.5f;
    float s0 = (v0 >= 1.f) ? 1.f : 0.f, s1 = (v1 >= 1.f) ? 1.f : 0.f;
    spk[o] = s0; spk[o + 64] = s1;
    v0 *= (1.f - s0); v1 *= (1.f - s1);
    u64 m = __ballot((s0 != 0.f) || (s1 != 0.f));
    if (lane == 0) flags[(size_t)tb * EE + e] = m ? 1 : 0;
  }
}

// ---------------- sparse spike GEMM, t-loop inside, fused BN + resid + LIF + flags ----------------
// grid (B, O/32, nz), block 256. Tile 32 o x 128 v; thread 4 o x 4 v; LIF state in regs.
__global__ __launch_bounds__(256) void gemm_fused(
    const float* __restrict__ In, const float* __restrict__ WT,
    float* __restrict__ OutPre, const float* __restrict__ resid,
    float* __restrict__ Spk, u8* __restrict__ flags,
    const float* __restrict__ bias, const float* __restrict__ bn1,
    const float* __restrict__ bn2, const u8* __restrict__ inFlags,
    int C, int O, float vth, long wtZ, long spkZ, long bnZ)
{
  const int b = blockIdx.x, ob = blockIdx.y * 32, z = blockIdx.z;
  const int tid = threadIdx.x, lane = tid & 63, wv = tid >> 6;
  WT += (long)z * wtZ; Spk += (long)z * spkZ;
  if (bn1) bn1 += (long)z * bnZ;
  if (bn2) bn2 += (long)z * bnZ;

  __shared__ float sIn[16][128];
  __shared__ float sW[16][32];
  __shared__ u16 slist[2048];
  __shared__ u32 wsum[4], woff[4], runb;

  const int og = (tid >> 5) * 4;     // 8 half-wave groups x 4 o
  const int vp = (tid & 31) * 4;
  const bool hasb = (bias != nullptr), has1 = (bn1 != nullptr), has2 = (bn2 != nullptr);

  float bs[4], m1[4], s1[4], b1[4], m2[4], s2[4], b2[4];
#pragma unroll
  for (int j = 0; j < 4; ++j) {
    int o = ob + og + j;
    bs[j] = hasb ? bias[o] : 0.f;
    if (has1) { float g = bn1[o]; b1[j] = bn1[O + o]; m1[j] = bn1[2 * O + o];
                s1[j] = g / sqrtf(bn1[3 * O + o] + BN_EPS); }
    if (has2) { float g = bn2[o]; b2[j] = bn2[O + o]; m2[j] = bn2[2 * O + o];
                s2[j] = g / sqrtf(bn2[3 * O + o] + BN_EPS); }
  }

  float st[4][4] = {};    // LIF membrane state across t

  for (int t = 0; t < TT; ++t) {
    // ---- build ascending active-channel list from producer flags ----
    __syncthreads();
    if (tid == 0) runb = 0;
    __syncthreads();
    const u8* F = inFlags + (size_t)(t * BB + b) * C;
    for (int c0 = 0; c0 < C; c0 += 256) {
      bool f = F[c0 + tid] != 0;
      u64 m = __ballot(f);
      if (lane == 0) wsum[wv] = __popcll(m);
      __syncthreads();
      if (tid == 0) { u32 s = runb;
#pragma unroll
        for (int k = 0; k < 4; ++k) { woff[k] = s; s += wsum[k]; } runb = s; }
      __syncthreads();
      if (f) { int rank = __popcll(m & ((1ull << lane) - 1));
               slist[woff[wv] + rank] = (u16)(c0 + tid); }
      __syncthreads();
    }
    const int n = (int)runb;
    const float* inB = In + (size_t)(t * BB + b) * C * VV;

    float acc[4][4] = {};
    int a0 = 0;
    while (a0 < n) {
      int m = n - a0; if (m > 16) m = 16;
      {
        int r0 = tid >> 5, q0 = (tid & 31) * 4;
        int r1 = r0 + 8;
        if (r0 < m) { int c = slist[a0 + r0]; *(float4*)&sIn[r0][q0] = *(const float4*)&inB[(size_t)c * VV + q0]; }
        if (r1 < m) { int c = slist[a0 + r1]; *(float4*)&sIn[r1][q0] = *(const float4*)&inB[(size_t)c * VV + q0]; }
        if (tid < 128) {
          int rw = tid >> 3, ow = (tid & 7) * 4;
          if (rw < m) { int c = slist[a0 + rw]; *(float4*)&sW[rw][ow] = *(const float4*)&WT[(size_t)c * O + ob + ow]; }
        }
      }
      __syncthreads();
      if (m == 16) {
#pragma unroll
        for (int cc = 0; cc < 16; ++cc) {
          float4 iv = *(const float4*)&sIn[cc][vp];
          float4 w4 = *(const float4*)&sW[cc][og];
          float wj[4] = {w4.x, w4.y, w4.z, w4.w};
#pragma unroll
          for (int j = 0; j < 4; ++j) {
            acc[j][0] += wj[j] * iv.x; acc[j][1] += wj[j] * iv.y;
            acc[j][2] += wj[j] * iv.z; acc[j][3] += wj[j] * iv.w;
          }
        }
      } else {
        for (int cc = 0; cc < m; ++cc) {
          float4 iv = *(const float4*)&sIn[cc][vp];
          float4 w4 = *(const float4*)&sW[cc][og];
          float wj[4] = {w4.x, w4.y, w4.z, w4.w};
#pragma unroll
          for (int j = 0; j < 4; ++j) {
            acc[j][0] += wj[j] * iv.x; acc[j][1] += wj[j] * iv.y;
            acc[j][2] += wj[j] * iv.z; acc[j][3] += wj[j] * iv.w;
          }
        }
      }
      __syncthreads();
      a0 += 16;
    }

    // ---- epilogue: bias -> bn1 -> bn2 -> resid -> LIF -> spikes + flags ----
#pragma unroll
    for (int j = 0; j < 4; ++j) {
      float a[4] = {acc[j][0], acc[j][1], acc[j][2], acc[j][3]};
      if (hasb) {
#pragma unroll
        for (int k = 0; k < 4; ++k) a[k] += bs[j];
      }
      if (has1) {
#pragma unroll
        for (int k = 0; k < 4; ++k) a[k] = (a[k] - m1[j]) * s1[j] + b1[j];
      }
      if (has2) {
#pragma unroll
        for (int k = 0; k < 4; ++k) a[k] = (a[k] - m2[j]) * s2[j] + b2[j];
      }
      size_t oi = ((size_t)(t * BB + b) * O + ob + og + j) * VV + vp;
      if (OutPre) {
        float4 r = *(const float4*)&resid[oi];
        a[0] += r.x; a[1] += r.y; a[2] += r.z; a[3] += r.w;
        float4 wr = {a[0], a[1], a[2], a[3]};
        *(float4*)&OutPre[oi] = wr;
      }
      float sp[4];
#pragma unroll
      for (int k = 0; k < 4; ++k) {
        st[j][k] += (a[k] - st[j][k]) * 0.5f;
        sp[k] = (st[j][k] >= vth) ? 1.f : 0.f;
        st[j][k] *= (1.f - sp[k]);
      }
      float4 wsp = {sp[0], sp[1], sp[2], sp[3]};
      *(float4*)&Spk[oi] = wsp;
      bool any = (sp[0] + sp[1] + sp[2] + sp[3]) != 0.f;
      u64 mb = __ballot(any);
      if (flags) {
        size_t fb = (size_t)(t * BB + b) * O + ob;
        if (lane == 0)  flags[fb + wv * 8 + j]     = (mb & 0xffffffffull) ? 1 : 0;
        if (lane == 32) flags[fb + wv * 8 + 4 + j] = (mb >> 32) ? 1 : 0;
      }
    }
  }
}

// ---------------- attention: KV[tbh][c][d] = sum_n K[c,n]*V[d,n] ----------------
__global__ __launch_bounds__(256) void attn_kv(const float* __restrict__ K,
    const float* __restrict__ Vv, float* __restrict__ KV)
{
  const int tbh = blockIdx.x;
  const int tb = tbh >> 3, h = tbh & 7;
  const float* Kb = K + ((size_t)tb * EE + h * 64) * VV;
  const float* Vb = Vv + ((size_t)tb * EE + h * 64) * VV;
  __shared__ float sK[64][132], sV[64][132];
  const int tid = threadIdx.x;
#pragma unroll
  for (int i = 0; i < 8; ++i) {
    int idx = tid + i * 256;
    int r = idx >> 5, col = (idx & 31) * 4;
    *(float4*)&sK[r][col] = *(const float4*)&Kb[r * VV + col];
    *(float4*)&sV[r][col] = *(const float4*)&Vb[r * VV + col];
  }
  __syncthreads();
  const int cg = (tid >> 4) * 4;
  const int dg = (tid & 15) * 4;
  float acc[4][4] = {};
#pragma unroll 4
  for (int n = 0; n < 128; n += 4) {
    float4 ks[4], vs[4];
#pragma unroll
    for (int i = 0; i < 4; ++i) ks[i] = *(const float4*)&sK[cg + i][n];
#pragma unroll
    for (int j = 0; j < 4; ++j) vs[j] = *(const float4*)&sV[dg + j][n];
#pragma unroll
    for (int i = 0; i < 4; ++i)
#pragma unroll
      for (int j = 0; j < 4; ++j)
        acc[i][j] += ks[i].x * vs[j].x + ks[i].y * vs[j].y +
                     ks[i].z * vs[j].z + ks[i].w * vs[j].w;
  }
#pragma unroll
  for (int i = 0; i < 4; ++i)
#pragma unroll
    for (int j = 0; j < 4; ++j)
      KV[((size_t)tbh * 64 + cg + i) * 64 + dg + j] = acc[i][j];
}

// ---------------- attention O = 0.125*Q.KV, fused LIF(0.5) + flags; t-loop inside ----------------
// grid (B, 8 heads, 2 d-halves), block 256. Tile 32 d x 128 n.
__global__ __launch_bounds__(256) void attn_o_lif(const float* __restrict__ Q,
    const float* __restrict__ KV, float* __restrict__ Spk, u8* __restrict__ flags)
{
  const int b = blockIdx.x, hh = blockIdx.y, dh = blockIdx.z;
  const int tid = threadIdx.x, lane = tid & 63;
  __shared__ float sQ[64][132];
  __shared__ float sKV[64][40];
  const int np = (tid & 63) * 2;
  const int dgl = (tid >> 6) * 8;
  float st[8][2] = {};
  for (int t = 0; t < TT; ++t) {
    const int tb = t * BB + b, tbh = tb * 8 + hh;
    const float* Qb = Q + ((size_t)tb * EE + hh * 64) * VV;
#pragma unroll
    for (int i = 0; i < 8; ++i) {
      int idx = tid + i * 256;
      int r = idx >> 5, col = (idx & 31) * 4;
      *(float4*)&sQ[r][col] = *(const float4*)&Qb[(size_t)r * VV + col];
    }
    const float* KVb = KV + (size_t)tbh * 4096 + dh * 32;
#pragma unroll
    for (int i = 0; i < 8; ++i) {
      int idx = tid + i * 256;
      int c = idx >> 5, dl = idx & 31;
      sKV[c][dl] = KVb[(size_t)c * 64 + dl];
    }
    __syncthreads();
    float acc[8][2] = {};
#pragma unroll 4
    for (int c = 0; c < 64; ++c) {
      float2 q2 = *(const float2*)&sQ[c][np];
      float4 wa = *(const float4*)&sKV[c][dgl];
      float4 wb = *(const float4*)&sKV[c][dgl + 4];
      float w8[8] = {wa.x, wa.y, wa.z, wa.w, wb.x, wb.y, wb.z, wb.w};
#pragma unroll
      for (int i = 0; i < 8; ++i) { acc[i][0] += w8[i] * q2.x; acc[i][1] += w8[i] * q2.y; }
    }
#pragma unroll
    for (int i = 0; i < 8; ++i) {
      float a0 = acc[i][0] * 0.125f, a1 = acc[i][1] * 0.125f;
      st[i][0] += (a0 - st[i][0]) * 0.5f; st[i][1] += (a1 - st[i][1]) * 0.5f;
      float s0 = (st[i][0] >= 0.5f) ? 1.f : 0.f, s1 = (st[i][1] >= 0.5f) ? 1.f : 0.f;
      size_t oi = ((size_t)tb * EE + hh * 64 + dh * 32 + dgl + i) * VV + np;
      Spk[oi] = s0; Spk[oi + 1] = s1;
      st[i][0] *= (1.f - s0); st[i][1] *= (1.f - s1);
      u64 m = __ballot((s0 != 0.f) || (s1 != 0.f));
      if (lane == 0) flags[(size_t)tb * EE + hh * 64 + dh * 32 + dgl + i] = m ? 1 : 0;
    }
    __syncthreads();
  }
}

// ---------------- head: mean over V then LIF over t (thread per (b,e)) ----------------
__global__ __launch_bounds__(256) void mean_lif(const float* __restrict__ h,
    float* __restrict__ sh)
{
  int i = blockIdx.x * 256 + threadIdx.x;   // b*EE + e, total 8192
  float v = 0.f;
#pragma unroll
  for (int t = 0; t < TT; ++t) {
    const float* p = h + ((size_t)t * BB * EE + i) * VV;
    float s = 0.f;
#pragma unroll
    for (int q = 0; q < VV; q += 4) {
      float4 x = *(const float4*)&p[q];
      s += x.x + x.y + x.z + x.w;
    }
    float hm = s * (1.f / 128.f);
    v += (hm - v) * 0.5f;
    float sp = (v >= 1.f) ? 1.f : 0.f;
    sh[(size_t)t * (BB * EE) + i] = sp;
    v *= (1.f - sp);
  }
}

// ---------------- head linear: wave per (b,n) ----------------
__global__ __launch_bounds__(256) void head_k2(const float* __restrict__ sh,
    const float* __restrict__ hw, const float* __restrict__ hb,
    float* __restrict__ out)
{
  int g = blockIdx.x * 4 + (threadIdx.x >> 6);
  int lane = threadIdx.x & 63;
  if (g >= BB * 11) return;
  int b = g / 11, n = g % 11;
  float s = 0.f;
#pragma unroll
  for (int t = 0; t < TT; ++t) {
    const float* sp = sh + (size_t)t * (BB * EE) + b * EE;
    const float* wp = hw + n * EE;
    float ss = 0.f;
#pragma unroll
    for (int e = 0; e < EE; e += 64) ss += sp[e + lane] * wp[e + lane];
#pragma unroll
    for (int off = 32; off; off >>= 1) ss += __shfl_down(ss, off);
    if (lane == 0) s += ss;
  }
  if (lane == 0) out[g] = s * 0.25f + hb[n];
}

// ---------------- launch ----------------
extern "C" void kernel_launch(void* const* d_in, const int* in_sizes, int n_in,
                              void* d_out, int out_size, void* d_ws, size_t ws_size,
                              hipStream_t stream) {
  const float* x       = (const float*)d_in[0];
  const float* pe_w    = (const float*)d_in[1];
  const float* pe_bn   = (const float*)d_in[2];
  const float* qkvp_w  = (const float*)d_in[3];
  const float* qkvp_bn = (const float*)d_in[4];
  const float* fc1_w   = (const float*)d_in[5];
  const float* fc1_b   = (const float*)d_in[6];
  const float* fc1_bn  = (const float*)d_in[7];
  const float* fc2_w   = (const float*)d_in[8];
  const float* fc2_b   = (const float*)d_in[9];
  const float* fc2_bn  = (const float*)d_in[10];
  const float* head_w  = (const float*)d_in[11];
  const float* head_b  = (const float*)d_in[12];
  float* out = (float*)d_out;

  const size_t NH = (size_t)TT * BB * EE * VV;   // 4194304
  float* ws    = (float*)d_ws;
  float* h     = ws;
  float* bufS  = h + NH;
  float* bufQ  = bufS + NH;
  float* bufK  = bufQ + NH;
  float* bufV  = bufK + NH;
  float* bufO  = bufV + NH;
  float* bufKV = bufO + NH;                      // 512*64*64
  float* bufHid = bufQ;                          // overlay: exactly spans Q..O
  float* wtA   = bufKV + (size_t)512 * 64 * 64;  // 4*E*E
  float* wtF1  = wtA + (size_t)4 * EE * EE;      // HID*E
  float* wtF2  = wtF1 + (size_t)HIDC * EE;       // E*HID
  float* sh    = wtF2 + (size_t)EE * HIDC;       // T*B*E
  u8*    flagsA = (u8*)(sh + (size_t)TT * BB * EE);   // 64*512
  u8*    flagsB = flagsA + (size_t)TT * BB * EE;      // 64*512
  u8*    flagsH = flagsB + (size_t)TT * BB * EE;      // 64*2048

  pe_lif<<<BB * EE / 4, 256, 0, stream>>>(x, pe_w, pe_bn, h, bufS, flagsA);

  for (int d = 0; d < 6; ++d) {
    trans6<<<dim3(1024, 6), 256, 0, stream>>>(
        qkvp_w + (size_t)d * 4 * EE * EE,
        fc1_w + (size_t)d * HIDC * EE,
        fc2_w + (size_t)d * EE * HIDC, wtA, wtF1, wtF2);

    const float* bn1p = qkvp_bn + (size_t)d * 4 * 2 * 4 * EE;

    // qkv (z=3): sparse gemm + bn1 + bn2 + LIF(1) -> spike Q/K/V (no flags)
    gemm_fused<<<dim3(BB, 16, 3), 256, 0, stream>>>(bufS, wtA, nullptr, nullptr,
        bufQ, nullptr, nullptr, bn1p, bn1p + 4 * EE, flagsA,
        EE, EE, 1.f, (long)EE * EE, (long)NH, (long)2 * 4 * EE);
    attn_kv<<<512, 256, 0, stream>>>(bufK, bufV, bufKV);
    attn_o_lif<<<dim3(BB, 8, 2), 256, 0, stream>>>(bufQ, bufKV, bufO, flagsB);
    // proj: + resid -> h, fused MLP-input LIF(1) -> bufS spikes + flagsA
    gemm_fused<<<dim3(BB, 16, 1), 256, 0, stream>>>(bufO, wtA + (size_t)3 * EE * EE,
        h, h, bufS, flagsA, nullptr,
        bn1p + 3 * (2 * 4 * EE), bn1p + 3 * (2 * 4 * EE) + 4 * EE, flagsB,
        EE, EE, 1.f, 0, 0, 0);
    // fc1: bias + bn + LIF(1) -> bufHid spikes + flagsH
    gemm_fused<<<dim3(BB, 64, 1), 256, 0, stream>>>(bufS, wtF1, nullptr, nullptr,
        bufHid, flagsH, fc1_b + (size_t)d * HIDC, fc1_bn + (size_t)d * 4 * HIDC,
        nullptr, flagsA, EE, HIDC, 1.f, 0, 0, 0);
    // fc2: bias + bn + resid -> h, fused next-layer attention LIF(1) -> bufS + flagsA
    gemm_fused<<<dim3(BB, 16, 1), 256, 0, stream>>>(bufHid, wtF2, h, h,
        bufS, flagsA, fc2_b + (size_t)d * EE, fc2_bn + (size_t)d * 4 * EE,
        nullptr, flagsH, HIDC, EE, 1.f, 0, 0, 0);
  }

  mean_lif<<<32, 256, 0, stream>>>(h, sh);
  head_k2<<<44, 256, 0, stream>>>(sh, head_w, head_b, out);
}

// Round 5
// 602.921 us; speedup vs baseline: 1.7752x; 1.7752x over previous
//
#include <hip/hip_runtime.h>

#define TT 4
#define BB 16
#define VV 128
#define EE 512
#define HIDC 2048
#define BN_EPS 1e-5f

typedef unsigned int u32;
typedef unsigned long long u64;
typedef unsigned short u16;

// ---------------- all-layer weight transpose: WT[c][o] ----------------
__global__ __launch_bounds__(256) void trans_all(const float* __restrict__ qw,
    const float* __restrict__ f1w, const float* __restrict__ f2w,
    float* __restrict__ wq, float* __restrict__ w1, float* __restrict__ w2)
{
  const int d = blockIdx.z, zz = blockIdx.y;
  const float* src; float* dst; int O, C;
  if (zz < 4)      { src = qw + ((size_t)d * 4 + zz) * EE * EE; dst = wq + ((size_t)d * 4 + zz) * EE * EE; O = EE; C = EE; }
  else if (zz == 4){ src = f1w + (size_t)d * HIDC * EE; dst = w1 + (size_t)d * HIDC * EE; O = HIDC; C = EE; }
  else             { src = f2w + (size_t)d * EE * HIDC; dst = w2 + (size_t)d * EE * HIDC; O = EE; C = HIDC; }
  const int tc_n = C >> 5, to_n = O >> 5;
  const int bx = blockIdx.x;
  if (bx >= tc_n * to_n) return;
  const int tc = bx % tc_n, to = bx / tc_n;
  __shared__ float t[32][33];
  const int tx = threadIdx.x & 31, ty = threadIdx.x >> 5;
#pragma unroll
  for (int k = 0; k < 4; ++k) {
    int o = to * 32 + ty + k * 8, c = tc * 32 + tx;
    t[ty + k * 8][tx] = src[(size_t)o * C + c];
  }
  __syncthreads();
#pragma unroll
  for (int k = 0; k < 4; ++k) {
    int c = tc * 32 + ty + k * 8, o = to * 32 + tx;
    dst[(size_t)c * O + o] = t[tx][ty + k * 8];
  }
}

// ---------------- patch embed + BN + LIF -> h (fp32) + spike MASKS ----------------
// wave = one (b,e) channel; lane owns v=lane and v=lane+64.
__global__ __launch_bounds__(256) void pe_lif(const float* __restrict__ x,
    const float* __restrict__ w, const float* __restrict__ bnp,
    float* __restrict__ h, u32* __restrict__ mIn)
{
  const int g = blockIdx.x * 4 + (threadIdx.x >> 6);
  const int lane = threadIdx.x & 63;
  const int b = g >> 9, e = g & 511;
  const float w0 = w[e * 2], w1 = w[e * 2 + 1];
  const float gg = bnp[e], be = bnp[EE + e], mm = bnp[2 * EE + e], vr = bnp[3 * EE + e];
  const float sc = gg / sqrtf(vr + BN_EPS);
  float v0 = 0.f, v1 = 0.f;
#pragma unroll
  for (int t = 0; t < TT; ++t) {
    const int tb = t * BB + b;
    const float* xb = x + (size_t)tb * 2 * VV;
    float a0 = (w0 * xb[lane]      + w1 * xb[VV + lane]      - mm) * sc + be;
    float a1 = (w0 * xb[lane + 64] + w1 * xb[VV + lane + 64] - mm) * sc + be;
    size_t o = ((size_t)tb * EE + e) * VV + lane;
    h[o] = a0; h[o + 64] = a1;
    v0 += (a0 - v0) * 0.5f; v1 += (a1 - v1) * 0.5f;
    float s0 = (v0 >= 1.f) ? 1.f : 0.f, s1 = (v1 >= 1.f) ? 1.f : 0.f;
    v0 *= (1.f - s0); v1 *= (1.f - s1);
    u64 m0 = __ballot(s0 != 0.f);
    u64 m1 = __ballot(s1 != 0.f);
    if (lane == 0) {
      uint4 mw = {(u32)m0, (u32)(m0 >> 32), (u32)m1, (u32)(m1 >> 32)};
      *(uint4*)&mIn[((size_t)tb * EE + e) * 4] = mw;
    }
  }
}

// ---------------- sparse bit-spike GEMM, t inside, fused BN+resid+LIF -> masks ----------------
// InM: [TB][C][4] u32 masks. WT: [C][O] (+z*wtZ). grid (B, O/16, nz), 256 thr.
// Thread: 2 o x 4 v. Active list rebuilt per (t) from mask rows (ascending c = exact order).
__global__ __launch_bounds__(256) void gemm_fused(
    const u32* __restrict__ InM, const float* __restrict__ WT,
    float* __restrict__ OutPre, const float* __restrict__ resid,
    u32* __restrict__ SpkM, const float* __restrict__ bias,
    const float* __restrict__ bn1, const float* __restrict__ bn2,
    int C, int O, float vth, long wtZ, long spkZ, long bnZ)
{
  const int b = blockIdx.x, ob = blockIdx.y * 16, z = blockIdx.z;
  const int tid = threadIdx.x, lane = tid & 63, wv = tid >> 6;
  WT += (long)z * wtZ; SpkM += (long)z * spkZ;
  if (bn1) bn1 += (long)z * bnZ;
  if (bn2) bn2 += (long)z * bnZ;

  __shared__ float sW[16][16];
  __shared__ u32 sM[16][4];
  __shared__ u16 slist[2048];
  __shared__ u32 wsum[4], woff[4], runb;

  const int og = (tid >> 5) * 2;
  const bool hasb = (bias != nullptr), has1 = (bn1 != nullptr), has2 = (bn2 != nullptr);

  float bs[2], m1c[2], s1c[2], b1c[2], m2c[2], s2c[2], b2c[2];
#pragma unroll
  for (int j = 0; j < 2; ++j) {
    int o = ob + og + j;
    bs[j] = hasb ? bias[o] : 0.f;
    if (has1) { float g = bn1[o]; b1c[j] = bn1[O + o]; m1c[j] = bn1[2 * O + o];
                s1c[j] = g / sqrtf(bn1[3 * O + o] + BN_EPS); }
    if (has2) { float g = bn2[o]; b2c[j] = bn2[O + o]; m2c[j] = bn2[2 * O + o];
                s2c[j] = g / sqrtf(bn2[3 * O + o] + BN_EPS); }
  }

  float st[2][4] = {};

  for (int t = 0; t < TT; ++t) {
    const u32* Mrow = InM + (size_t)(t * BB + b) * C * 4;
    // ---- build ascending active list from mask rows ----
    __syncthreads();
    if (tid == 0) runb = 0;
    __syncthreads();
    for (int c0 = 0; c0 < C; c0 += 256) {
      uint4 r = *(const uint4*)&Mrow[(size_t)(c0 + tid) * 4];
      bool f = (r.x | r.y | r.z | r.w) != 0;
      u64 m = __ballot(f);
      if (lane == 0) wsum[wv] = __popcll(m);
      __syncthreads();
      if (tid == 0) { u32 s = runb;
#pragma unroll
        for (int k = 0; k < 4; ++k) { woff[k] = s; s += wsum[k]; } runb = s; }
      __syncthreads();
      if (f) { int rank = __popcll(m & ((1ull << lane) - 1));
               slist[woff[wv] + rank] = (u16)(c0 + tid); }
      __syncthreads();
    }
    const int n = (int)runb;

    float acc[2][4] = {};
    int a0 = 0;
    while (a0 < n) {
      int m = n - a0; if (m > 16) m = 16;
      if (tid < 64) {
        int cc = tid >> 2, q = tid & 3;
        if (cc < m) {
          int c = slist[a0 + cc];
          sM[cc][q] = Mrow[(size_t)c * 4 + q];
          *(float4*)&sW[cc][q * 4] = *(const float4*)&WT[(size_t)c * O + ob + q * 4];
        }
      }
      __syncthreads();
#pragma unroll 4
      for (int cc = 0; cc < m; ++cc) {
        u32 mw = sM[cc][(tid & 31) >> 3];
        u32 nib = mw >> ((tid & 7) * 4);
        float2 w2 = *(const float2*)&sW[cc][og];
        float i0 = (nib & 1u) ? 1.f : 0.f;
        float i1 = (nib & 2u) ? 1.f : 0.f;
        float i2 = (nib & 4u) ? 1.f : 0.f;
        float i3 = (nib & 8u) ? 1.f : 0.f;
        acc[0][0] += w2.x * i0; acc[0][1] += w2.x * i1;
        acc[0][2] += w2.x * i2; acc[0][3] += w2.x * i3;
        acc[1][0] += w2.y * i0; acc[1][1] += w2.y * i1;
        acc[1][2] += w2.y * i2; acc[1][3] += w2.y * i3;
      }
      __syncthreads();
      a0 += 16;
    }

    // ---- epilogue: bias -> bn1 -> bn2 -> resid -> LIF -> mask assembly ----
#pragma unroll
    for (int j = 0; j < 2; ++j) {
      float a[4] = {acc[j][0], acc[j][1], acc[j][2], acc[j][3]};
      if (hasb) {
#pragma unroll
        for (int k = 0; k < 4; ++k) a[k] += bs[j];
      }
      if (has1) {
#pragma unroll
        for (int k = 0; k < 4; ++k) a[k] = (a[k] - m1c[j]) * s1c[j] + b1c[j];
      }
      if (has2) {
#pragma unroll
        for (int k = 0; k < 4; ++k) a[k] = (a[k] - m2c[j]) * s2c[j] + b2c[j];
      }
      size_t orow = (size_t)(t * BB + b) * O + ob + og + j;
      if (OutPre) {
        size_t oi = orow * VV + (tid & 31) * 4;
        float4 r = *(const float4*)&resid[oi];
        a[0] += r.x; a[1] += r.y; a[2] += r.z; a[3] += r.w;
        float4 wr = {a[0], a[1], a[2], a[3]};
        *(float4*)&OutPre[oi] = wr;
      }
      u32 nib = 0;
#pragma unroll
      for (int k = 0; k < 4; ++k) {
        st[j][k] += (a[k] - st[j][k]) * 0.5f;
        float sp = (st[j][k] >= vth) ? 1.f : 0.f;
        st[j][k] *= (1.f - sp);
        nib |= (sp != 0.f) ? (1u << k) : 0u;
      }
      u32 wmask = nib << ((tid & 7) * 4);
      wmask |= __shfl_xor(wmask, 1);
      wmask |= __shfl_xor(wmask, 2);
      wmask |= __shfl_xor(wmask, 4);
      if ((tid & 7) == 0) SpkM[orow * 4 + ((tid & 31) >> 3)] = wmask;
    }
  }
}

// ---------------- fused attention: KV=popcount(K&V); O=Q.KV*0.125; LIF(0.5) -> masks ----
// grid (B, 8 heads, 2 d-halves), 256 thr, t inside.
__global__ __launch_bounds__(256) void attn_fused(const u32* __restrict__ Qm,
    const u32* __restrict__ Km, const u32* __restrict__ Vm, u32* __restrict__ Om)
{
  const int b = blockIdx.x, hh = blockIdx.y, dh = blockIdx.z;
  const int tid = threadIdx.x, lane = tid & 63;
  __shared__ float sQ[64][132];
  __shared__ float sKV[64][36];
  __shared__ u64 sKm[64][2], sQm[64][2], sVm[32][2];
  __shared__ u32 sQnz[64];
  const int np = lane * 2;
  const int dg = (tid >> 6) * 8;
  float st[8][2] = {};
  for (int t = 0; t < TT; ++t) {
    const int tb = t * BB + b;
    __syncthreads();
    if (tid < 64) {
      uint4 q = *(const uint4*)&Qm[((size_t)tb * EE + hh * 64 + tid) * 4];
      sQm[tid][0] = ((u64)q.y << 32) | q.x; sQm[tid][1] = ((u64)q.w << 32) | q.z;
      sQnz[tid] = q.x | q.y | q.z | q.w;
      uint4 k = *(const uint4*)&Km[((size_t)tb * EE + hh * 64 + tid) * 4];
      sKm[tid][0] = ((u64)k.y << 32) | k.x; sKm[tid][1] = ((u64)k.w << 32) | k.z;
    } else if (tid < 96) {
      int d = tid - 64;
      uint4 v = *(const uint4*)&Vm[((size_t)tb * EE + hh * 64 + dh * 32 + d) * 4];
      sVm[d][0] = ((u64)v.y << 32) | v.x; sVm[d][1] = ((u64)v.w << 32) | v.z;
    }
    __syncthreads();
    // KV: thread (c = tid>>2, 8 d's)
    {
      int c = tid >> 2, dq = (tid & 3) * 8;
      u64 k0 = sKm[c][0], k1 = sKm[c][1];
#pragma unroll
      for (int i = 0; i < 8; ++i) {
        int d = dq + i;
        int p = __popcll(k0 & sVm[d][0]) + __popcll(k1 & sVm[d][1]);
        sKV[c][d] = (float)p;
      }
    }
    // Q bits -> floats
    {
      int c = tid >> 2, nq = (tid & 3) * 32;
      u64 qw = sQm[c][nq >> 6] >> (nq & 32);
#pragma unroll
      for (int kk = 0; kk < 8; ++kk) {
        float4 f = {(qw >> (kk * 4)) & 1 ? 1.f : 0.f,
                    (qw >> (kk * 4 + 1)) & 1 ? 1.f : 0.f,
                    (qw >> (kk * 4 + 2)) & 1 ? 1.f : 0.f,
                    (qw >> (kk * 4 + 3)) & 1 ? 1.f : 0.f};
        *(float4*)&sQ[c][nq + kk * 4] = f;
      }
    }
    __syncthreads();
    float acc[8][2] = {};
    for (int c = 0; c < 64; ++c) {
      if (!sQnz[c]) continue;
      float2 q2 = *(const float2*)&sQ[c][np];
      float4 wa = *(const float4*)&sKV[c][dg];
      float4 wb = *(const float4*)&sKV[c][dg + 4];
      float w8[8] = {wa.x, wa.y, wa.z, wa.w, wb.x, wb.y, wb.z, wb.w};
#pragma unroll
      for (int i = 0; i < 8; ++i) { acc[i][0] += w8[i] * q2.x; acc[i][1] += w8[i] * q2.y; }
    }
#pragma unroll
    for (int i = 0; i < 8; ++i) {
      float a0 = acc[i][0] * 0.125f, a1 = acc[i][1] * 0.125f;
      st[i][0] += (a0 - st[i][0]) * 0.5f; st[i][1] += (a1 - st[i][1]) * 0.5f;
      float s0 = (st[i][0] >= 0.5f) ? 1.f : 0.f, s1 = (st[i][1] >= 0.5f) ? 1.f : 0.f;
      st[i][0] *= (1.f - s0); st[i][1] *= (1.f - s1);
      u32 two = ((s0 != 0.f) ? 1u : 0u) | ((s1 != 0.f) ? 2u : 0u);
      u32 wmask = two << ((lane & 15) * 2);
      wmask |= __shfl_xor(wmask, 1);
      wmask |= __shfl_xor(wmask, 2);
      wmask |= __shfl_xor(wmask, 4);
      wmask |= __shfl_xor(wmask, 8);
      if ((lane & 15) == 0)
        Om[((size_t)tb * EE + hh * 64 + dh * 32 + dg + i) * 4 + (lane >> 4)] = wmask;
    }
  }
}

// ---------------- head: mean over V then LIF over t ----------------
__global__ __launch_bounds__(256) void mean_lif(const float* __restrict__ h,
    float* __restrict__ sh)
{
  int i = blockIdx.x * 256 + threadIdx.x;
  float v = 0.f;
#pragma unroll
  for (int t = 0; t < TT; ++t) {
    const float* p = h + ((size_t)t * BB * EE + i) * VV;
    float s = 0.f;
#pragma unroll
    for (int q = 0; q < VV; q += 4) {
      float4 x = *(const float4*)&p[q];
      s += x.x + x.y + x.z + x.w;
    }
    float hm = s * (1.f / 128.f);
    v += (hm - v) * 0.5f;
    float sp = (v >= 1.f) ? 1.f : 0.f;
    sh[(size_t)t * (BB * EE) + i] = sp;
    v *= (1.f - sp);
  }
}

__global__ __launch_bounds__(256) void head_k2(const float* __restrict__ sh,
    const float* __restrict__ hw, const float* __restrict__ hb,
    float* __restrict__ out)
{
  int g = blockIdx.x * 4 + (threadIdx.x >> 6);
  int lane = threadIdx.x & 63;
  if (g >= BB * 11) return;
  int b = g / 11, n = g % 11;
  float s = 0.f;
#pragma unroll
  for (int t = 0; t < TT; ++t) {
    const float* sp = sh + (size_t)t * (BB * EE) + b * EE;
    const float* wp = hw + n * EE;
    float ss = 0.f;
#pragma unroll
    for (int e = 0; e < EE; e += 64) ss += sp[e + lane] * wp[e + lane];
#pragma unroll
    for (int off = 32; off; off >>= 1) ss += __shfl_down(ss, off);
    if (lane == 0) s += ss;
  }
  if (lane == 0) out[g] = s * 0.25f + hb[n];
}

// ---------------- launch ----------------
extern "C" void kernel_launch(void* const* d_in, const int* in_sizes, int n_in,
                              void* d_out, int out_size, void* d_ws, size_t ws_size,
                              hipStream_t stream) {
  const float* x       = (const float*)d_in[0];
  const float* pe_w    = (const float*)d_in[1];
  const float* pe_bn   = (const float*)d_in[2];
  const float* qkvp_w  = (const float*)d_in[3];
  const float* qkvp_bn = (const float*)d_in[4];
  const float* fc1_w   = (const float*)d_in[5];
  const float* fc1_b   = (const float*)d_in[6];
  const float* fc1_bn  = (const float*)d_in[7];
  const float* fc2_w   = (const float*)d_in[8];
  const float* fc2_b   = (const float*)d_in[9];
  const float* fc2_bn  = (const float*)d_in[10];
  const float* head_w  = (const float*)d_in[11];
  const float* head_b  = (const float*)d_in[12];
  float* out = (float*)d_out;

  const size_t NH = (size_t)TT * BB * EE * VV;       // 4194304
  float* ws = (float*)d_ws;
  float* h   = ws;
  float* wq  = h + NH;                               // 6*4*E*E
  float* w1  = wq + (size_t)6 * 4 * EE * EE;         // 6*HID*E
  float* w2  = w1 + (size_t)6 * HIDC * EE;           // 6*E*HID
  float* sh  = w2 + (size_t)6 * EE * HIDC;           // T*B*E
  u32* mIn  = (u32*)(sh + (size_t)TT * BB * EE);
  u32* mQKV = mIn + (size_t)64 * EE * 4;
  u32* mO   = mQKV + (size_t)3 * 64 * EE * 4;
  u32* mMlp = mO + (size_t)64 * EE * 4;
  u32* mHid = mMlp + (size_t)64 * EE * 4;            // 64*HIDC*4

  u32* mQ = mQKV;
  u32* mK = mQKV + (size_t)64 * EE * 4;
  u32* mV = mQKV + (size_t)2 * 64 * EE * 4;

  trans_all<<<dim3(1024, 6, 6), 256, 0, stream>>>(qkvp_w, fc1_w, fc2_w, wq, w1, w2);
  pe_lif<<<BB * EE / 4, 256, 0, stream>>>(x, pe_w, pe_bn, h, mIn);

  for (int d = 0; d < 6; ++d) {
    const float* bn1p = qkvp_bn + (size_t)d * 4 * 2 * 4 * EE;
    // qkv (z=3): masks in -> Q/K/V masks
    gemm_fused<<<dim3(BB, EE / 16, 3), 256, 0, stream>>>(mIn,
        wq + (size_t)d * 4 * EE * EE, nullptr, nullptr, mQ, nullptr,
        bn1p, bn1p + 4 * EE, EE, EE, 1.f,
        (long)EE * EE, (long)64 * EE * 4, (long)2 * 4 * EE);
    attn_fused<<<dim3(BB, 8, 2), 256, 0, stream>>>(mQ, mK, mV, mO);
    // proj: + resid -> h; LIF(1) -> mMlp
    gemm_fused<<<dim3(BB, EE / 16, 1), 256, 0, stream>>>(mO,
        wq + ((size_t)d * 4 + 3) * EE * EE, h, h, mMlp, nullptr,
        bn1p + 3 * (2 * 4 * EE), bn1p + 3 * (2 * 4 * EE) + 4 * EE,
        EE, EE, 1.f, 0, 0, 0);
    // fc1: bias+bn; LIF(1) -> mHid
    gemm_fused<<<dim3(BB, HIDC / 16, 1), 256, 0, stream>>>(mMlp,
        w1 + (size_t)d * HIDC * EE, nullptr, nullptr, mHid,
        fc1_b + (size_t)d * HIDC, fc1_bn + (size_t)d * 4 * HIDC, nullptr,
        EE, HIDC, 1.f, 0, 0, 0);
    // fc2: bias+bn + resid -> h; LIF(1) -> mIn (next layer's attention input)
    gemm_fused<<<dim3(BB, EE / 16, 1), 256, 0, stream>>>(mHid,
        w2 + (size_t)d * EE * HIDC, h, h, mIn,
        fc2_b + (size_t)d * EE, fc2_bn + (size_t)d * 4 * EE, nullptr,
        HIDC, EE, 1.f, 0, 0, 0);
  }

  mean_lif<<<32, 256, 0, stream>>>(h, sh);
  head_k2<<<44, 256, 0, stream>>>(sh, head_w, head_b, out);
}